// Round 19
// baseline (197.470 us; speedup 1.0000x reference)
//
#include <hip/hip_runtime.h>
#include <hip/hip_fp16.h>
#include <stdint.h>

// Problem constants (match reference)
#define N_NODES  50000
#define N_EDGES  800000
#define D        256
#define D_OUT    16
#define N_GRAPHS 128
#define NB_SCAN  196        // 196*256 = 50176 >= N_NODES+1
#define FILL_NB  3125       // N_EDGES/256

// JAX jax_threefry_partitionable=True: bits32(i) = fold(threefry2x32((0,42),(0,i))),
// fold = o0 ^ o1; keep iff top bit == 0.  (verified round 2, absmax 0.0)
// r17: fp8 h storage (agg fetch 187->87MB). r18 lesson: do NOT fuse a
// no-LDS latency-bound path (fill) with a 72KB-LDS path (gemm) — static LDS
// reservation caps the fill path at 2 blocks/CU (78us vs 50 serial).
// r19: keep [wt|edeg] prep fusion; gemm and fill stay separate kernels.

typedef short bf16x8 __attribute__((ext_vector_type(8)));
typedef float f32x4  __attribute__((ext_vector_type(4)));
typedef float f32x2  __attribute__((ext_vector_type(2)));

__device__ __forceinline__ uint32_t rotl32(uint32_t x, int d) {
    return (x << d) | (x >> (32 - d));
}

__device__ __forceinline__ void threefry2x32(uint32_t k0, uint32_t k1,
                                             uint32_t c0, uint32_t c1,
                                             uint32_t& o0, uint32_t& o1) {
    uint32_t ks2 = k0 ^ k1 ^ 0x1BD11BDAu;
    uint32_t x0 = c0 + k0, x1 = c1 + k1;
    x0 += x1; x1 = rotl32(x1, 13); x1 ^= x0;
    x0 += x1; x1 = rotl32(x1, 15); x1 ^= x0;
    x0 += x1; x1 = rotl32(x1, 26); x1 ^= x0;
    x0 += x1; x1 = rotl32(x1, 6);  x1 ^= x0;
    x0 += k1; x1 += ks2 + 1u;
    x0 += x1; x1 = rotl32(x1, 17); x1 ^= x0;
    x0 += x1; x1 = rotl32(x1, 29); x1 ^= x0;
    x0 += x1; x1 = rotl32(x1, 16); x1 ^= x0;
    x0 += x1; x1 = rotl32(x1, 24); x1 ^= x0;
    x0 += ks2; x1 += k0 + 2u;
    x0 += x1; x1 = rotl32(x1, 13); x1 ^= x0;
    x0 += x1; x1 = rotl32(x1, 15); x1 ^= x0;
    x0 += x1; x1 = rotl32(x1, 26); x1 ^= x0;
    x0 += x1; x1 = rotl32(x1, 6);  x1 ^= x0;
    x0 += k0; x1 += k1 + 3u;
    x0 += x1; x1 = rotl32(x1, 17); x1 ^= x0;
    x0 += x1; x1 = rotl32(x1, 29); x1 ^= x0;
    x0 += x1; x1 = rotl32(x1, 16); x1 ^= x0;
    x0 += x1; x1 = rotl32(x1, 24); x1 ^= x0;
    x0 += k1; x1 += ks2 + 4u;
    x0 += x1; x1 = rotl32(x1, 13); x1 ^= x0;
    x0 += x1; x1 = rotl32(x1, 15); x1 ^= x0;
    x0 += x1; x1 = rotl32(x1, 26); x1 ^= x0;
    x0 += x1; x1 = rotl32(x1, 6);  x1 ^= x0;
    x0 += ks2; x1 += k0 + 5u;
    o0 = x0; o1 = x1;
}

__device__ __forceinline__ bool dropout_keep(uint32_t i) {
    uint32_t o0, o1;
    threefry2x32(0u, 42u, 0u, i, o0, o1);
    return ((o0 ^ o1) & 0x80000000u) == 0u;
}

__device__ __forceinline__ uint32_t bf16_rne(float f) {   // fp32 -> bf16 bits (RNE)
    uint32_t u = __float_as_uint(f);
    return (u + 0x7FFFu + ((u >> 16) & 1u)) >> 16;
}

// FUSED: blocks 0..15 = W transpose to bf16 wt[n][k]; 16.. = edeg f64 atomics
// (degsum zeroed by memset before this launch). Both paths LDS-light.
__global__ __launch_bounds__(256) void k_prep(const float* __restrict__ W,
                                              ushort* __restrict__ wt,
                                              const int* __restrict__ ei,
                                              const float* __restrict__ ew,
                                              double* __restrict__ degsum) {
    int t = threadIdx.x;
    if (blockIdx.x < 16) {
        __shared__ float td[64][65];
        int kb = blockIdx.x & 3, nb = blockIdx.x >> 2;   // 4x4 tiles of 64x64
        int nl = t & 63, r4 = t >> 6;
#pragma unroll
        for (int i = 0; i < 16; i++) {
            int kl = r4 + 4 * i;
            td[kl][nl] = W[(size_t)(kb * 64 + kl) * 256 + nb * 64 + nl];
        }
        __syncthreads();
        int kp = t & 31, nl2 = t >> 5;
        uint32_t* wt32 = (uint32_t*)wt;
#pragma unroll
        for (int i = 0; i < 8; i++) {
            int n = nl2 + 8 * i;
            uint32_t p = bf16_rne(td[2 * kp][n]) | (bf16_rne(td[2 * kp + 1][n]) << 16);
            wt32[((size_t)(nb * 64 + n) * 256 + kb * 64 + 2 * kp) >> 1] = p;
        }
    } else {
        int e = (blockIdx.x - 16) * 256 + t;   // exactly 800000 threads
        int c = ei[N_EDGES + e];
        atomicAdd(&degsum[c], 4294967296.0 + (double)ew[e]);
    }
}

// scan phase 1: degsum -> dinv + cnt(start[i]); per-block reduce of counts
__global__ __launch_bounds__(256) void k_scan1(const double* __restrict__ degsum,
                                               float* __restrict__ dinv,
                                               int* __restrict__ start,
                                               int* __restrict__ partial) {
    __shared__ int sd[256];
    int t = threadIdx.x;
    int i = blockIdx.x * 256 + t;
    int cnt = 0;
    if (i < N_NODES) {
        double val = degsum[i];
        cnt = (int)(val * (1.0 / 4294967296.0));          // exact
        float deg = (float)(val - (double)cnt * 4294967296.0) + 1.0f;  // +self-loop
        dinv[i] = rsqrtf(deg);                             // deg >= 1 always
        start[i] = cnt;
    }
    sd[t] = cnt;
    __syncthreads();
    for (int d = 128; d > 0; d >>= 1) {
        if (t < d) sd[t] += sd[t + d];
        __syncthreads();
    }
    if (t == 0) partial[blockIdx.x] = sd[0];
}

// scan phase 2+3 fused: redundant block-scan of the 196 partials in LDS, then
// per-block chunk scan -> start[] (EXCLUSIVE prefix). No cursor: k_fill bumps
// start in place; after fill, start[n] == end of node n (end-pointer trick).
__global__ __launch_bounds__(256) void k_scan3(int* __restrict__ start,
                                               const int* __restrict__ partial) {
    __shared__ int sp[256];
    __shared__ int so[256];
    __shared__ int sd[256];
    int t = threadIdx.x;
    int pv = (t < NB_SCAN) ? partial[t] : 0;
    sp[t] = pv; so[t] = pv;
    __syncthreads();
    for (int d = 1; d < 256; d <<= 1) {
        int u = (t >= d) ? sp[t - d] : 0;
        __syncthreads();
        sp[t] += u;
        __syncthreads();
    }
    int base = sp[blockIdx.x] - so[blockIdx.x];    // exclusive prefix of this block

    int i = blockIdx.x * 256 + t;
    int v = (i < N_NODES) ? start[i] : 0;
    sd[t] = v;
    __syncthreads();
    for (int d = 1; d < 256; d <<= 1) {
        int u = (t >= d) ? sd[t - d] : 0;
        __syncthreads();
        sd[t] += u;
        __syncthreads();
    }
    if (i < N_NODES) start[i] = base + sd[t] - v;  // exclusive prefix
}

// scatter each edge's (row*32, raw f32 ew) into its CSR slot; bumps start[].
// NO LDS -> full occupancy for atomic-latency hiding.
__global__ __launch_bounds__(256) void k_fill(const int* __restrict__ ei,
                                              const float* __restrict__ ew,
                                              int* __restrict__ start,
                                              int2* __restrict__ edge) {
    int e = blockIdx.x * 256 + threadIdx.x;   // exactly 800000 threads
    int r = ei[e];
    int c = ei[N_EDGES + e];
    int pos = atomicAdd(&start[c], 1);
    edge[pos] = make_int2(r * 32, __float_as_int(ew[e]));  // 32 uint2 per fp8 row
}

// ---------------- MFMA GEMM: h'(fp8 e4m3) = dinv[row] * (x @ W1) -----------
__device__ __forceinline__ int swz(int row, int kByte) {
    return (row << 9) + (kByte ^ ((row & 7) << 4));
}

__global__ __launch_bounds__(256) void k_gemm(const float* __restrict__ x,
                                              const ushort* __restrict__ wt,
                                              const float* __restrict__ dinv,
                                              uint8_t* __restrict__ hb) {
    __shared__ __align__(16) char smem[73728];   // A:[0,32K) Bt:[32K,64K) C:[64K,72K)
    __shared__ float sdinv[64];
    int tid = threadIdx.x;
    int Mbase = blockIdx.x * 64;

    if (tid < 64) {
        int node = Mbase + tid; if (node >= N_NODES) node = N_NODES - 1;
        sdinv[tid] = dinv[node];
    }
    // stage A: x[Mbase..+63][0..255] -> bf16, swizzled
    const float4* xv = (const float4*)x;
#pragma unroll
    for (int i = 0; i < 16; i++) {
        int f = tid + i * 256;        // flat float4 id, 0..4095
        int r = f >> 6;               // row 0..63
        int c4 = f & 63;              // float4 index -> k = 4*c4
        int node = Mbase + r; if (node >= N_NODES) node = N_NODES - 1;
        float4 v = xv[(size_t)node * 64 + c4];
        uint32_t p0 = bf16_rne(v.x) | (bf16_rne(v.y) << 16);
        uint32_t p1 = bf16_rne(v.z) | (bf16_rne(v.w) << 16);
        *(uint2*)(smem + swz(r, c4 * 8)) = make_uint2(p0, p1);
    }

    int l = tid & 63;
    int w = tid >> 6;
    int wr = w >> 1, wc = w & 1;          // wave grid 2x2, each 32x32
    int lr = l & 15;
    int kg = l >> 4;
    int drow = (l >> 4) * 4;
    int dcol = l & 15;
    const uint4* wt4 = (const uint4*)wt;  // 16B units; 32 per 512B row
    ushort* c_lds = (ushort*)(smem + 65536);   // [64][64] fp16 tile

    for (int nb = 0; nb < 4; nb++) {
        // stage Bt tile: wt rows nb*64..+63 (coalesced uint4 copy)
#pragma unroll
        for (int i = 0; i < 8; i++) {
            int f = tid + i * 256;    // 0..2047 uint4
            int r = f >> 5;           // row 0..63
            int c = f & 31;           // 16B chunk
            uint4 v = wt4[(size_t)(nb * 64 + r) * 32 + c];
            *(uint4*)(smem + 32768 + swz(r, c * 16)) = v;
        }
        __syncthreads();              // Bt ready; prev copy-out done

        f32x4 acc00 = {0.f, 0.f, 0.f, 0.f};
        f32x4 acc01 = acc00, acc10 = acc00, acc11 = acc00;
#pragma unroll
        for (int ks = 0; ks < 8; ks++) {
            int kB = ks * 64 + kg * 16;
            bf16x8 a0 = *(const bf16x8*)(smem + swz(wr * 32 + lr, kB));
            bf16x8 a1 = *(const bf16x8*)(smem + swz(wr * 32 + 16 + lr, kB));
            bf16x8 b0 = *(const bf16x8*)(smem + 32768 + swz(wc * 32 + lr, kB));
            bf16x8 b1 = *(const bf16x8*)(smem + 32768 + swz(wc * 32 + 16 + lr, kB));
            acc00 = __builtin_amdgcn_mfma_f32_16x16x32_bf16(a0, b0, acc00, 0, 0, 0);
            acc01 = __builtin_amdgcn_mfma_f32_16x16x32_bf16(a0, b1, acc01, 0, 0, 0);
            acc10 = __builtin_amdgcn_mfma_f32_16x16x32_bf16(a1, b0, acc10, 0, 0, 0);
            acc11 = __builtin_amdgcn_mfma_f32_16x16x32_bf16(a1, b1, acc11, 0, 0, 0);
        }
        // D layout row=(l>>4)*4+r, col=l&15 (m89); scale by dinv; fp16 C_lds
#pragma unroll
        for (int r = 0; r < 4; r++) {
            int lr0 = wr * 32 + drow + r;
            float s0 = sdinv[lr0], s1 = sdinv[lr0 + 16];
            int cc = wc * 32 + dcol;
            __half h00 = __float2half(acc00[r] * s0);
            __half h01 = __float2half(acc01[r] * s0);
            __half h10 = __float2half(acc10[r] * s1);
            __half h11 = __float2half(acc11[r] * s1);
            c_lds[lr0 * 64 + cc]             = *(ushort*)&h00;
            c_lds[lr0 * 64 + cc + 16]        = *(ushort*)&h01;
            c_lds[(lr0 + 16) * 64 + cc]      = *(ushort*)&h10;
            c_lds[(lr0 + 16) * 64 + cc + 16] = *(ushort*)&h11;
        }
        __syncthreads();              // C_lds complete
        // copy-out with fp16->fp8 convert: 512 uint2 (4KB), 2/thread
#pragma unroll
        for (int i = 0; i < 2; i++) {
            int idx = tid + i * 256;  // 0..511
            int r = idx >> 3;         // row 0..63
            int c8 = idx & 7;         // 8-col group
            uint4 v = ((const uint4*)c_lds)[idx];   // 8 fp16
            __half2* hp = (__half2*)&v;
            float f0 = __low2float(hp[0]), f1 = __high2float(hp[0]);
            float f2 = __low2float(hp[1]), f3 = __high2float(hp[1]);
            float f4 = __low2float(hp[2]), f5 = __high2float(hp[2]);
            float f6 = __low2float(hp[3]), f7 = __high2float(hp[3]);
            uint32_t w0 = __builtin_amdgcn_cvt_pk_fp8_f32(f0, f1, 0, false);
            w0 = __builtin_amdgcn_cvt_pk_fp8_f32(f2, f3, w0, true);
            uint32_t w1 = __builtin_amdgcn_cvt_pk_fp8_f32(f4, f5, 0, false);
            w1 = __builtin_amdgcn_cvt_pk_fp8_f32(f6, f7, w1, true);
            int node = Mbase + r;
            if (node < N_NODES)
                *(uint2*)(hb + (size_t)node * 256 + nb * 64 + c8 * 8) =
                    make_uint2(w0, w1);
        }
    }
}

// CSR aggregate (fp8 h, f32 accum): 8-edge batches, 8B/lane gathers,
// unguarded next-batch prefetch (padded edge array), inline threefry,
// block-level LDS pool flush. start[] is the post-fill end-pointer array.
__device__ __forceinline__ void fma8f(float* a, uint2 u, float w) {
    f32x2 p0 = __builtin_amdgcn_cvt_pk_f32_fp8(u.x, false);
    f32x2 p1 = __builtin_amdgcn_cvt_pk_f32_fp8(u.x, true);
    f32x2 p2 = __builtin_amdgcn_cvt_pk_f32_fp8(u.y, false);
    f32x2 p3 = __builtin_amdgcn_cvt_pk_f32_fp8(u.y, true);
    a[0] = fmaf(w, p0.x, a[0]); a[1] = fmaf(w, p0.y, a[1]);
    a[2] = fmaf(w, p1.x, a[2]); a[3] = fmaf(w, p1.y, a[3]);
    a[4] = fmaf(w, p2.x, a[4]); a[5] = fmaf(w, p2.y, a[5]);
    a[6] = fmaf(w, p3.x, a[6]); a[7] = fmaf(w, p3.y, a[7]);
}

__global__ __launch_bounds__(256) void k_agg(const int* __restrict__ start,
                                             const int2* __restrict__ edge,
                                             const uint8_t* __restrict__ hb,
                                             const float* __restrict__ dinv,
                                             const float* __restrict__ b1,
                                             const int* __restrict__ gidx,
                                             float* __restrict__ sums) {
    __shared__ float ls[4][256];
    int wid = threadIdx.x >> 6;
    int l = threadIdx.x & 63;
    int half = l >> 5;                     // 0: even edge slots, 1: odd
    int cl = l & 31;                       // 8B column chunk (cols 8cl..8cl+7)
    int n = blockIdx.x * 4 + wid;          // always < N_NODES
    const uint2* h8 = (const uint2*)hb;    // 32 uint2 per 256B row
    int e = start[n];                      // end-pointer array
    int s = (n == 0) ? 0 : start[n - 1];
    int last = e - 1;

    // independent loads issued early
    uint2 un = h8[(size_t)n * 32 + cl];
    float4 bv = ((const float4*)b1)[2 * cl + half];
    float dn = dinv[n];
    int gfirst = gidx[blockIdx.x * 4];
    int glast  = gidx[blockIdx.x * 4 + 3];

    int off = 4 * half;
    int col = 8 * cl + off;

    // first batch preload (unguarded: edge[] padded by 16 zero slots)
    int j = s;
    int2 E0, E1, E2, E3;
    if (j < e) {
        int i0 = j + half;
        E0 = edge[i0];
        E1 = edge[i0 + 2];
        E2 = edge[i0 + 4];
        E3 = edge[i0 + 6];
    }

    // dropout factors: threefry VALU hidden under the in-flight loads
    uint32_t base = (uint32_t)n * D + (uint32_t)col;
    float m0 = dropout_keep(base + 0u) ? 2.f : 0.f;
    float m1 = dropout_keep(base + 1u) ? 2.f : 0.f;
    float m2 = dropout_keep(base + 2u) ? 2.f : 0.f;
    float m3 = dropout_keep(base + 3u) ? 2.f : 0.f;

    float A0[8] = {0,0,0,0,0,0,0,0}, A1[8] = {0,0,0,0,0,0,0,0};

    // -------- main loop: batch fully valid, no clamps/selects --------
    for (; j + 8 <= e; j += 8) {
        uint2 u0 = h8[(size_t)(uint32_t)(E0.x + cl)];
        uint2 u1 = h8[(size_t)(uint32_t)(E1.x + cl)];
        uint2 u2 = h8[(size_t)(uint32_t)(E2.x + cl)];
        uint2 u3 = h8[(size_t)(uint32_t)(E3.x + cl)];
        float w0 = __int_as_float(E0.y);
        float w1 = __int_as_float(E1.y);
        float w2 = __int_as_float(E2.y);
        float w3 = __int_as_float(E3.y);
        // unguarded prefetch (reads at most edge[j+15]; array padded)
        int i0n = j + 8 + half;
        E0 = edge[i0n];
        E1 = edge[i0n + 2];
        E2 = edge[i0n + 4];
        E3 = edge[i0n + 6];
        fma8f(A0, u0, w0); fma8f(A1, u1, w1);
        fma8f(A0, u2, w2); fma8f(A1, u3, w3);
    }
    // -------- single masked tail iteration --------
    if (j < e) {
        uint2 u0 = h8[(size_t)(uint32_t)(E0.x + cl)];
        uint2 u1 = h8[(size_t)(uint32_t)(E1.x + cl)];
        uint2 u2 = h8[(size_t)(uint32_t)(E2.x + cl)];
        uint2 u3 = h8[(size_t)(uint32_t)(E3.x + cl)];
        int x0 = j + half, x1 = x0 + 2, x2 = x0 + 4, x3 = x0 + 6;
        float w0 = x0 <= last ? __int_as_float(E0.y) : 0.f;
        float w1 = x1 <= last ? __int_as_float(E1.y) : 0.f;
        float w2 = x2 <= last ? __int_as_float(E2.y) : 0.f;
        float w3 = x3 <= last ? __int_as_float(E3.y) : 0.f;
        fma8f(A0, u0, w0); fma8f(A1, u1, w1);
        fma8f(A0, u2, w2); fma8f(A1, u3, w3);
    }

    float full[8];
#pragma unroll
    for (int k = 0; k < 8; k++)
        full[k] = A0[k] + A1[k];
#pragma unroll
    for (int k = 0; k < 8; k++)
        full[k] += __shfl_xor(full[k], 32, 64);   // combine the two edge-halves

    // self-loop + bias + relu + dropout for this lane's 4 cols
    uint32_t word = half ? un.y : un.x;
    f32x2 q0 = __builtin_amdgcn_cvt_pk_f32_fp8(word, false);
    f32x2 q1 = __builtin_amdgcn_cvt_pk_f32_fp8(word, true);
    float v0 = fmaxf(dn * (full[off + 0] + q0.x) + bv.x, 0.f) * m0;
    float v1 = fmaxf(dn * (full[off + 1] + q0.y) + bv.y, 0.f) * m1;
    float v2 = fmaxf(dn * (full[off + 2] + q1.x) + bv.z, 0.f) * m2;
    float v3 = fmaxf(dn * (full[off + 3] + q1.y) + bv.w, 0.f) * m3;

    if (gfirst == glast) {                 // block-uniform branch (~99% of blocks)
        *(float4*)&ls[wid][col] = make_float4(v0, v1, v2, v3);
        __syncthreads();
        int t = threadIdx.x;
        float sv = (ls[0][t] + ls[1][t]) + (ls[2][t] + ls[3][t]);
        atomicAdd(&sums[(size_t)gfirst * D + t], sv);
    } else {                               // graph boundary inside block (rare)
        int g = gidx[n];
        float* sg = &sums[(size_t)g * D + col];
        atomicAdd(sg + 0, v0);
        atomicAdd(sg + 1, v1);
        atomicAdd(sg + 2, v2);
        atomicAdd(sg + 3, v3);
    }
}

// pooled = sums/cnt (cnt via binary search on sorted gidx); out = pooled@fcW+fcb
__global__ __launch_bounds__(256) void k_out(const float* __restrict__ sums,
                                             const int* __restrict__ gidx,
                                             const float* __restrict__ fcW,
                                             const float* __restrict__ fcb,
                                             float* __restrict__ out) {
    __shared__ int sh[2];
    __shared__ float p[D];
    int g = blockIdx.x, t = threadIdx.x;
    if (t == 0) {
        int lo = 0, hi = N_NODES;
        while (lo < hi) { int m = (lo + hi) >> 1; if (gidx[m] < g) lo = m + 1; else hi = m; }
        sh[0] = lo;
        int lo2 = lo; hi = N_NODES;
        while (lo2 < hi) { int m = (lo2 + hi) >> 1; if (gidx[m] < g + 1) lo2 = m + 1; else hi = m; }
        sh[1] = lo2;
    }
    __syncthreads();
    float c = fmaxf((float)(sh[1] - sh[0]), 1.0f);
    p[t] = sums[(size_t)g * D + t] / c;
    __syncthreads();
    if (t < D_OUT) {
        float acc = fcb[t];
        for (int k = 0; k < D; k++)
            acc = fmaf(p[k], fcW[k * D_OUT + t], acc);
        out[g * D_OUT + t] = acc;
    }
}

extern "C" void kernel_launch(void* const* d_in, const int* in_sizes, int n_in,
                              void* d_out, int out_size, void* d_ws, size_t ws_size,
                              hipStream_t stream) {
    const float* x   = (const float*)d_in[0];
    const int*   ei  = (const int*)d_in[1];
    const float* ew  = (const float*)d_in[2];
    const int*   gix = (const int*)d_in[3];
    const float* W1  = (const float*)d_in[4];
    const float* b1  = (const float*)d_in[5];
    const float* fcW = (const float*)d_in[6];
    const float* fcb = (const float*)d_in[7];
    float* out = (float*)d_out;

    float*   ws     = (float*)d_ws;
    float*   dinv   = ws;                                   //    65,536 f
    uint8_t* hb     = (uint8_t*)(ws + 65536);               // 12.8 MB fp8
    int2*    edge   = (int2*)(ws + 65536 + 3200000);        // 800,016 int2
    int*     start  = (int*)(edge + N_EDGES + 16);          //    65,536
    int*     partial    = start + 65536;                    //       256 (+pad)
    ushort*  wt     = (ushort*)(partial + 512);             //    65,536 us
    float*   sums   = (float*)(wt + 65536);                 //    32,768 f
    double*  degsum = (double*)(sums + 32768);              //    50,000 f64
    // total ~21 MB

    // per-call zero-init (replays don't re-poison)
    hipMemsetAsync(degsum, 0, N_NODES * sizeof(double), stream);
    hipMemsetAsync(sums, 0, N_GRAPHS * D * sizeof(float), stream);
    hipMemsetAsync(edge + N_EDGES, 0, 16 * sizeof(int2), stream);

    k_prep<<<16 + FILL_NB, 256, 0, stream>>>(W1, wt, ei, ew, degsum);
    k_scan1<<<NB_SCAN, 256, 0, stream>>>(degsum, dinv, start, partial);
    k_scan3<<<NB_SCAN, 256, 0, stream>>>(start, partial);
    k_fill<<<FILL_NB, 256, 0, stream>>>(ei, ew, start, edge);
    k_gemm<<<(N_NODES + 63) / 64, 256, 0, stream>>>(x, wt, dinv, hb);
    k_agg<<<N_NODES / 4, 256, 0, stream>>>(start, edge, hb, dinv, b1, gix, sums);
    k_out<<<N_GRAPHS, 256, 0, stream>>>(sums, gix, fcW, fcb, out);
}

// Round 20
// 157.823 us; speedup vs baseline: 1.2512x; 1.2512x over previous
//
#include <hip/hip_runtime.h>
#include <hip/hip_fp16.h>
#include <stdint.h>

// Problem constants (match reference)
#define N_NODES  50000
#define N_EDGES  800000
#define D        256
#define D_OUT    16
#define N_GRAPHS 128
#define NB_SCAN  196        // 196*256 = 50176 >= N_NODES (covers dinv/sums init)
#define FILL_NB  3125       // N_EDGES/256
#define BCAP     64         // bucket capacity; Poisson(16) max deg ~45 over 50k

// JAX jax_threefry_partitionable=True: bits32(i) = fold(threefry2x32((0,42),(0,i))),
// fold = o0 ^ o1; keep iff top bit == 0.  (verified round 2, absmax 0.0)
// r17: fp8 h (agg fetch 187->87MB). r20: CSR scan pipeline replaced by
// fixed-capacity buckets — ONE f64 atomic per edge returns the bucket slot
// (count in high bits) AND accumulates weighted degree. edeg+scan1+scan3 gone.

typedef short bf16x8 __attribute__((ext_vector_type(8)));
typedef float f32x4  __attribute__((ext_vector_type(4)));
typedef float f32x2  __attribute__((ext_vector_type(2)));

__device__ __forceinline__ uint32_t rotl32(uint32_t x, int d) {
    return (x << d) | (x >> (32 - d));
}

__device__ __forceinline__ void threefry2x32(uint32_t k0, uint32_t k1,
                                             uint32_t c0, uint32_t c1,
                                             uint32_t& o0, uint32_t& o1) {
    uint32_t ks2 = k0 ^ k1 ^ 0x1BD11BDAu;
    uint32_t x0 = c0 + k0, x1 = c1 + k1;
    x0 += x1; x1 = rotl32(x1, 13); x1 ^= x0;
    x0 += x1; x1 = rotl32(x1, 15); x1 ^= x0;
    x0 += x1; x1 = rotl32(x1, 26); x1 ^= x0;
    x0 += x1; x1 = rotl32(x1, 6);  x1 ^= x0;
    x0 += k1; x1 += ks2 + 1u;
    x0 += x1; x1 = rotl32(x1, 17); x1 ^= x0;
    x0 += x1; x1 = rotl32(x1, 29); x1 ^= x0;
    x0 += x1; x1 = rotl32(x1, 16); x1 ^= x0;
    x0 += x1; x1 = rotl32(x1, 24); x1 ^= x0;
    x0 += ks2; x1 += k0 + 2u;
    x0 += x1; x1 = rotl32(x1, 13); x1 ^= x0;
    x0 += x1; x1 = rotl32(x1, 15); x1 ^= x0;
    x0 += x1; x1 = rotl32(x1, 26); x1 ^= x0;
    x0 += x1; x1 = rotl32(x1, 6);  x1 ^= x0;
    x0 += k0; x1 += k1 + 3u;
    x0 += x1; x1 = rotl32(x1, 17); x1 ^= x0;
    x0 += x1; x1 = rotl32(x1, 29); x1 ^= x0;
    x0 += x1; x1 = rotl32(x1, 16); x1 ^= x0;
    x0 += x1; x1 = rotl32(x1, 24); x1 ^= x0;
    x0 += k1; x1 += ks2 + 4u;
    x0 += x1; x1 = rotl32(x1, 13); x1 ^= x0;
    x0 += x1; x1 = rotl32(x1, 15); x1 ^= x0;
    x0 += x1; x1 = rotl32(x1, 26); x1 ^= x0;
    x0 += x1; x1 = rotl32(x1, 6);  x1 ^= x0;
    x0 += ks2; x1 += k0 + 5u;
    o0 = x0; o1 = x1;
}

__device__ __forceinline__ bool dropout_keep(uint32_t i) {
    uint32_t o0, o1;
    threefry2x32(0u, 42u, 0u, i, o0, o1);
    return ((o0 ^ o1) & 0x80000000u) == 0u;
}

__device__ __forceinline__ uint32_t bf16_rne(float f) {   // fp32 -> bf16 bits (RNE)
    uint32_t u = __float_as_uint(f);
    return (u + 0x7FFFu + ((u >> 16) & 1u)) >> 16;
}

// FUSED build: blocks 0..15 = W transpose to bf16 wt[n][k] (16.6KB LDS, still
// >=8 blocks/CU — resource-compatible per r18 lesson); blocks 16.. = bucket
// scatter. ONE f64 atomic per edge: old value's high bits = bucket slot;
// fraction accumulates weighted degree. degsum pre-zeroed by memset.
__global__ __launch_bounds__(256) void k_build(const float* __restrict__ W,
                                               ushort* __restrict__ wt,
                                               const int* __restrict__ ei,
                                               const float* __restrict__ ew,
                                               double* __restrict__ degsum,
                                               int2* __restrict__ bucket) {
    int t = threadIdx.x;
    if (blockIdx.x < 16) {
        __shared__ float td[64][65];
        int kb = blockIdx.x & 3, nb = blockIdx.x >> 2;   // 4x4 tiles of 64x64
        int nl = t & 63, r4 = t >> 6;
#pragma unroll
        for (int i = 0; i < 16; i++) {
            int kl = r4 + 4 * i;
            td[kl][nl] = W[(size_t)(kb * 64 + kl) * 256 + nb * 64 + nl];
        }
        __syncthreads();
        int kp = t & 31, nl2 = t >> 5;
        uint32_t* wt32 = (uint32_t*)wt;
#pragma unroll
        for (int i = 0; i < 8; i++) {
            int n = nl2 + 8 * i;
            uint32_t p = bf16_rne(td[2 * kp][n]) | (bf16_rne(td[2 * kp + 1][n]) << 16);
            wt32[((size_t)(nb * 64 + n) * 256 + kb * 64 + 2 * kp) >> 1] = p;
        }
    } else {
        int e = (blockIdx.x - 16) * 256 + t;   // exactly 800000 threads
        int r = ei[e];
        int c = ei[N_EDGES + e];
        float w = ew[e];
        double old = atomicAdd(&degsum[c], 4294967296.0 + (double)w);
        int pos = (int)(old * (1.0 / 4294967296.0));     // prior count = slot
        bucket[(size_t)c * BCAP + pos] = make_int2(r * 32, __float_as_int(w));
    }
}

// dinv + per-node count from degsum; also zeroes sums (runs before gemm/agg)
__global__ __launch_bounds__(256) void k_dinv(const double* __restrict__ degsum,
                                              float* __restrict__ dinv,
                                              int* __restrict__ cnt,
                                              float* __restrict__ sums) {
    int i = blockIdx.x * 256 + threadIdx.x;
    if (i < N_NODES) {
        double val = degsum[i];
        int c = (int)(val * (1.0 / 4294967296.0));        // exact
        float deg = (float)(val - (double)c * 4294967296.0) + 1.0f;  // +self-loop
        dinv[i] = rsqrtf(deg);                             // deg >= 1 always
        cnt[i] = c;
    }
    if (i < N_GRAPHS * D) sums[i] = 0.0f;
}

// ---------------- MFMA GEMM: h'(fp8 e4m3) = dinv[row] * (x @ W1) -----------
__device__ __forceinline__ int swz(int row, int kByte) {
    return (row << 9) + (kByte ^ ((row & 7) << 4));
}

__global__ __launch_bounds__(256) void k_gemm(const float* __restrict__ x,
                                              const ushort* __restrict__ wt,
                                              const float* __restrict__ dinv,
                                              uint8_t* __restrict__ hb) {
    __shared__ __align__(16) char smem[73728];   // A:[0,32K) Bt:[32K,64K) C:[64K,72K)
    __shared__ float sdinv[64];
    int tid = threadIdx.x;
    int Mbase = blockIdx.x * 64;

    if (tid < 64) {
        int node = Mbase + tid; if (node >= N_NODES) node = N_NODES - 1;
        sdinv[tid] = dinv[node];
    }
    // stage A: x[Mbase..+63][0..255] -> bf16, swizzled
    const float4* xv = (const float4*)x;
#pragma unroll
    for (int i = 0; i < 16; i++) {
        int f = tid + i * 256;        // flat float4 id, 0..4095
        int r = f >> 6;               // row 0..63
        int c4 = f & 63;              // float4 index -> k = 4*c4
        int node = Mbase + r; if (node >= N_NODES) node = N_NODES - 1;
        float4 v = xv[(size_t)node * 64 + c4];
        uint32_t p0 = bf16_rne(v.x) | (bf16_rne(v.y) << 16);
        uint32_t p1 = bf16_rne(v.z) | (bf16_rne(v.w) << 16);
        *(uint2*)(smem + swz(r, c4 * 8)) = make_uint2(p0, p1);
    }

    int l = tid & 63;
    int w = tid >> 6;
    int wr = w >> 1, wc = w & 1;          // wave grid 2x2, each 32x32
    int lr = l & 15;
    int kg = l >> 4;
    int drow = (l >> 4) * 4;
    int dcol = l & 15;
    const uint4* wt4 = (const uint4*)wt;  // 16B units; 32 per 512B row
    ushort* c_lds = (ushort*)(smem + 65536);   // [64][64] fp16 tile

    for (int nb = 0; nb < 4; nb++) {
        // stage Bt tile: wt rows nb*64..+63 (coalesced uint4 copy)
#pragma unroll
        for (int i = 0; i < 8; i++) {
            int f = tid + i * 256;    // 0..2047 uint4
            int r = f >> 5;           // row 0..63
            int c = f & 31;           // 16B chunk
            uint4 v = wt4[(size_t)(nb * 64 + r) * 32 + c];
            *(uint4*)(smem + 32768 + swz(r, c * 16)) = v;
        }
        __syncthreads();              // Bt ready; prev copy-out done

        f32x4 acc00 = {0.f, 0.f, 0.f, 0.f};
        f32x4 acc01 = acc00, acc10 = acc00, acc11 = acc00;
#pragma unroll
        for (int ks = 0; ks < 8; ks++) {
            int kB = ks * 64 + kg * 16;
            bf16x8 a0 = *(const bf16x8*)(smem + swz(wr * 32 + lr, kB));
            bf16x8 a1 = *(const bf16x8*)(smem + swz(wr * 32 + 16 + lr, kB));
            bf16x8 b0 = *(const bf16x8*)(smem + 32768 + swz(wc * 32 + lr, kB));
            bf16x8 b1 = *(const bf16x8*)(smem + 32768 + swz(wc * 32 + 16 + lr, kB));
            acc00 = __builtin_amdgcn_mfma_f32_16x16x32_bf16(a0, b0, acc00, 0, 0, 0);
            acc01 = __builtin_amdgcn_mfma_f32_16x16x32_bf16(a0, b1, acc01, 0, 0, 0);
            acc10 = __builtin_amdgcn_mfma_f32_16x16x32_bf16(a1, b0, acc10, 0, 0, 0);
            acc11 = __builtin_amdgcn_mfma_f32_16x16x32_bf16(a1, b1, acc11, 0, 0, 0);
        }
        // D layout row=(l>>4)*4+r, col=l&15 (m89); scale by dinv; fp16 C_lds
#pragma unroll
        for (int r = 0; r < 4; r++) {
            int lr0 = wr * 32 + drow + r;
            float s0 = sdinv[lr0], s1 = sdinv[lr0 + 16];
            int cc = wc * 32 + dcol;
            __half h00 = __float2half(acc00[r] * s0);
            __half h01 = __float2half(acc01[r] * s0);
            __half h10 = __float2half(acc10[r] * s1);
            __half h11 = __float2half(acc11[r] * s1);
            c_lds[lr0 * 64 + cc]             = *(ushort*)&h00;
            c_lds[lr0 * 64 + cc + 16]        = *(ushort*)&h01;
            c_lds[(lr0 + 16) * 64 + cc]      = *(ushort*)&h10;
            c_lds[(lr0 + 16) * 64 + cc + 16] = *(ushort*)&h11;
        }
        __syncthreads();              // C_lds complete
        // copy-out with fp16->fp8 convert: 512 uint2 (4KB), 2/thread
#pragma unroll
        for (int i = 0; i < 2; i++) {
            int idx = tid + i * 256;  // 0..511
            int r = idx >> 3;         // row 0..63
            int c8 = idx & 7;         // 8-col group
            uint4 v = ((const uint4*)c_lds)[idx];   // 8 fp16
            __half2* hp = (__half2*)&v;
            float f0 = __low2float(hp[0]), f1 = __high2float(hp[0]);
            float f2 = __low2float(hp[1]), f3 = __high2float(hp[1]);
            float f4 = __low2float(hp[2]), f5 = __high2float(hp[2]);
            float f6 = __low2float(hp[3]), f7 = __high2float(hp[3]);
            uint32_t w0 = __builtin_amdgcn_cvt_pk_fp8_f32(f0, f1, 0, false);
            w0 = __builtin_amdgcn_cvt_pk_fp8_f32(f2, f3, w0, true);
            uint32_t w1 = __builtin_amdgcn_cvt_pk_fp8_f32(f4, f5, 0, false);
            w1 = __builtin_amdgcn_cvt_pk_fp8_f32(f6, f7, w1, true);
            int node = Mbase + r;
            if (node < N_NODES)
                *(uint2*)(hb + (size_t)node * 256 + nb * 64 + c8 * 8) =
                    make_uint2(w0, w1);
        }
    }
}

// Bucket aggregate (fp8 h, f32 accum): s = n*BCAP, e = s + cnt[n].
// Main loop: unguarded prefetch, consumes only fully-valid batches.
// Tail: RELOADS with clamped slot indices (never dereferences garbage slots
// beyond cnt — poison-safe on first call). Inline threefry; LDS pool flush.
__device__ __forceinline__ void fma8f(float* a, uint2 u, float w) {
    f32x2 p0 = __builtin_amdgcn_cvt_pk_f32_fp8(u.x, false);
    f32x2 p1 = __builtin_amdgcn_cvt_pk_f32_fp8(u.x, true);
    f32x2 p2 = __builtin_amdgcn_cvt_pk_f32_fp8(u.y, false);
    f32x2 p3 = __builtin_amdgcn_cvt_pk_f32_fp8(u.y, true);
    a[0] = fmaf(w, p0.x, a[0]); a[1] = fmaf(w, p0.y, a[1]);
    a[2] = fmaf(w, p1.x, a[2]); a[3] = fmaf(w, p1.y, a[3]);
    a[4] = fmaf(w, p2.x, a[4]); a[5] = fmaf(w, p2.y, a[5]);
    a[6] = fmaf(w, p3.x, a[6]); a[7] = fmaf(w, p3.y, a[7]);
}

__global__ __launch_bounds__(256) void k_agg(const int* __restrict__ cnt,
                                             const int2* __restrict__ bucket,
                                             const uint8_t* __restrict__ hb,
                                             const float* __restrict__ dinv,
                                             const float* __restrict__ b1,
                                             const int* __restrict__ gidx,
                                             float* __restrict__ sums) {
    __shared__ float ls[4][256];
    int wid = threadIdx.x >> 6;
    int l = threadIdx.x & 63;
    int half = l >> 5;                     // 0: even edge slots, 1: odd
    int cl = l & 31;                       // 8B column chunk (cols 8cl..8cl+7)
    int n = blockIdx.x * 4 + wid;          // always < N_NODES
    const uint2* h8 = (const uint2*)hb;    // 32 uint2 per 256B row
    int cn = cnt[n];
    int s = n * BCAP;
    int e = s + cn;
    int last = e - 1;

    // independent loads issued early
    uint2 un = h8[(size_t)n * 32 + cl];
    float4 bv = ((const float4*)b1)[2 * cl + half];
    float dn = dinv[n];
    int gfirst = gidx[blockIdx.x * 4];
    int glast  = gidx[blockIdx.x * 4 + 3];

    int off = 4 * half;
    int col = 8 * cl + off;

    // first batch preload (reads within this node's 64-slot bucket; values
    // beyond cnt are garbage but only consumed when the batch is fully valid)
    int j = s;
    int2 E0, E1, E2, E3;
    if (j < e) {
        int i0 = j + half;
        E0 = bucket[i0];
        E1 = bucket[i0 + 2];
        E2 = bucket[i0 + 4];
        E3 = bucket[i0 + 6];
    }

    // dropout factors: threefry VALU hidden under the in-flight loads
    uint32_t base = (uint32_t)n * D + (uint32_t)col;
    float m0 = dropout_keep(base + 0u) ? 2.f : 0.f;
    float m1 = dropout_keep(base + 1u) ? 2.f : 0.f;
    float m2 = dropout_keep(base + 2u) ? 2.f : 0.f;
    float m3 = dropout_keep(base + 3u) ? 2.f : 0.f;

    float A0[8] = {0,0,0,0,0,0,0,0}, A1[8] = {0,0,0,0,0,0,0,0};

    // -------- main loop: batch fully valid, no clamps/selects --------
    for (; j + 8 <= e; j += 8) {
        uint2 u0 = h8[(size_t)(uint32_t)(E0.x + cl)];
        uint2 u1 = h8[(size_t)(uint32_t)(E1.x + cl)];
        uint2 u2 = h8[(size_t)(uint32_t)(E2.x + cl)];
        uint2 u3 = h8[(size_t)(uint32_t)(E3.x + cl)];
        float w0 = __int_as_float(E0.y);
        float w1 = __int_as_float(E1.y);
        float w2 = __int_as_float(E2.y);
        float w3 = __int_as_float(E3.y);
        // unguarded prefetch: stays inside this node's 64-slot bucket
        int i0n = j + 8 + half;
        E0 = bucket[i0n];
        E1 = bucket[i0n + 2];
        E2 = bucket[i0n + 4];
        E3 = bucket[i0n + 6];
        fma8f(A0, u0, w0); fma8f(A1, u1, w1);
        fma8f(A0, u2, w2); fma8f(A1, u3, w3);
    }
    // -------- tail: RELOAD with clamped slot indices (poison-safe) --------
    if (j < e) {
        int x0 = j + half, x1 = x0 + 2, x2 = x0 + 4, x3 = x0 + 6;
        int c0 = x0 < last ? x0 : last;
        int c1 = x1 < last ? x1 : last;
        int c2 = x2 < last ? x2 : last;
        int c3 = x3 < last ? x3 : last;
        int2 F0 = bucket[c0], F1 = bucket[c1], F2 = bucket[c2], F3 = bucket[c3];
        uint2 u0 = h8[(size_t)(uint32_t)(F0.x + cl)];
        uint2 u1 = h8[(size_t)(uint32_t)(F1.x + cl)];
        uint2 u2 = h8[(size_t)(uint32_t)(F2.x + cl)];
        uint2 u3 = h8[(size_t)(uint32_t)(F3.x + cl)];
        float w0 = x0 <= last ? __int_as_float(F0.y) : 0.f;
        float w1 = x1 <= last ? __int_as_float(F1.y) : 0.f;
        float w2 = x2 <= last ? __int_as_float(F2.y) : 0.f;
        float w3 = x3 <= last ? __int_as_float(F3.y) : 0.f;
        fma8f(A0, u0, w0); fma8f(A1, u1, w1);
        fma8f(A0, u2, w2); fma8f(A1, u3, w3);
    }

    float full[8];
#pragma unroll
    for (int k = 0; k < 8; k++)
        full[k] = A0[k] + A1[k];
#pragma unroll
    for (int k = 0; k < 8; k++)
        full[k] += __shfl_xor(full[k], 32, 64);   // combine the two edge-halves

    // self-loop + bias + relu + dropout for this lane's 4 cols
    uint32_t word = half ? un.y : un.x;
    f32x2 q0 = __builtin_amdgcn_cvt_pk_f32_fp8(word, false);
    f32x2 q1 = __builtin_amdgcn_cvt_pk_f32_fp8(word, true);
    float v0 = fmaxf(dn * (full[off + 0] + q0.x) + bv.x, 0.f) * m0;
    float v1 = fmaxf(dn * (full[off + 1] + q0.y) + bv.y, 0.f) * m1;
    float v2 = fmaxf(dn * (full[off + 2] + q1.x) + bv.z, 0.f) * m2;
    float v3 = fmaxf(dn * (full[off + 3] + q1.y) + bv.w, 0.f) * m3;

    if (gfirst == glast) {                 // block-uniform branch (~99% of blocks)
        *(float4*)&ls[wid][col] = make_float4(v0, v1, v2, v3);
        __syncthreads();
        int t = threadIdx.x;
        float sv = (ls[0][t] + ls[1][t]) + (ls[2][t] + ls[3][t]);
        atomicAdd(&sums[(size_t)gfirst * D + t], sv);
    } else {                               // graph boundary inside block (rare)
        int g = gidx[n];
        float* sg = &sums[(size_t)g * D + col];
        atomicAdd(sg + 0, v0);
        atomicAdd(sg + 1, v1);
        atomicAdd(sg + 2, v2);
        atomicAdd(sg + 3, v3);
    }
}

// pooled = sums/cnt (cnt via binary search on sorted gidx); out = pooled@fcW+fcb
__global__ __launch_bounds__(256) void k_out(const float* __restrict__ sums,
                                             const int* __restrict__ gidx,
                                             const float* __restrict__ fcW,
                                             const float* __restrict__ fcb,
                                             float* __restrict__ out) {
    __shared__ int sh[2];
    __shared__ float p[D];
    int g = blockIdx.x, t = threadIdx.x;
    if (t == 0) {
        int lo = 0, hi = N_NODES;
        while (lo < hi) { int m = (lo + hi) >> 1; if (gidx[m] < g) lo = m + 1; else hi = m; }
        sh[0] = lo;
        int lo2 = lo; hi = N_NODES;
        while (lo2 < hi) { int m = (lo2 + hi) >> 1; if (gidx[m] < g + 1) lo2 = m + 1; else hi = m; }
        sh[1] = lo2;
    }
    __syncthreads();
    float c = fmaxf((float)(sh[1] - sh[0]), 1.0f);
    p[t] = sums[(size_t)g * D + t] / c;
    __syncthreads();
    if (t < D_OUT) {
        float acc = fcb[t];
        for (int k = 0; k < D; k++)
            acc = fmaf(p[k], fcW[k * D_OUT + t], acc);
        out[g * D_OUT + t] = acc;
    }
}

extern "C" void kernel_launch(void* const* d_in, const int* in_sizes, int n_in,
                              void* d_out, int out_size, void* d_ws, size_t ws_size,
                              hipStream_t stream) {
    const float* x   = (const float*)d_in[0];
    const int*   ei  = (const int*)d_in[1];
    const float* ew  = (const float*)d_in[2];
    const int*   gix = (const int*)d_in[3];
    const float* W1  = (const float*)d_in[4];
    const float* b1  = (const float*)d_in[5];
    const float* fcW = (const float*)d_in[6];
    const float* fcb = (const float*)d_in[7];
    float* out = (float*)d_out;

    float*   ws     = (float*)d_ws;
    float*   dinv   = ws;                                   //     65,536 f
    uint8_t* hb     = (uint8_t*)(ws + 65536);               //  12.8 MB fp8
    int2*    bucket = (int2*)(ws + 65536 + 3200000);        //  50000*64 int2 = 25.6MB
    int*     cnt    = (int*)(bucket + (size_t)N_NODES * BCAP); //  65,536
    ushort*  wt     = (ushort*)(cnt + 65536);               //     65,536 us
    float*   sums   = (float*)(wt + 65536);                 //     32,768 f
    double*  degsum = (double*)(sums + 32768);              //     50,000 f64
    // total ~40 MB

    // per-call zero-init (replays don't re-poison)
    hipMemsetAsync(degsum, 0, N_NODES * sizeof(double), stream);

    k_build<<<16 + FILL_NB, 256, 0, stream>>>(W1, wt, ei, ew, degsum, bucket);
    k_dinv<<<NB_SCAN, 256, 0, stream>>>(degsum, dinv, cnt, sums);
    k_gemm<<<(N_NODES + 63) / 64, 256, 0, stream>>>(x, wt, dinv, hb);
    k_agg<<<N_NODES / 4, 256, 0, stream>>>(cnt, bucket, hb, dinv, b1, gix, sums);
    k_out<<<N_GRAPHS, 256, 0, stream>>>(sums, gix, fcW, fcb, out);
}

// Round 21
// 156.535 us; speedup vs baseline: 1.2615x; 1.0082x over previous
//
#include <hip/hip_runtime.h>
#include <hip/hip_fp16.h>
#include <stdint.h>

// Problem constants (match reference)
#define N_NODES  50000
#define N_EDGES  800000
#define D        256
#define D_OUT    16
#define N_GRAPHS 128
#define FILL_NB  3125       // N_EDGES/256
#define BCAP     64         // bucket capacity; Poisson(16) max deg ~45 over 50k

// JAX jax_threefry_partitionable=True: bits32(i) = fold(threefry2x32((0,42),(0,i))),
// fold = o0 ^ o1; keep iff top bit == 0.  (verified round 2, absmax 0.0)
// r20: fixed-capacity buckets via one f64 atomic (slot in high bits + weighted
// degree in fraction). r21: 4B bucket records (row<<16 | fp16 ew) halve build's
// random-store traffic; v_cvt_pk_bf16_f32 for gemm A-staging; k_dinv fused
// into gemm prologue (4 kernels + 1 memset total).

typedef short bf16x8 __attribute__((ext_vector_type(8)));
typedef float f32x4  __attribute__((ext_vector_type(4)));
typedef float f32x2  __attribute__((ext_vector_type(2)));

__device__ __forceinline__ uint32_t rotl32(uint32_t x, int d) {
    return (x << d) | (x >> (32 - d));
}

__device__ __forceinline__ void threefry2x32(uint32_t k0, uint32_t k1,
                                             uint32_t c0, uint32_t c1,
                                             uint32_t& o0, uint32_t& o1) {
    uint32_t ks2 = k0 ^ k1 ^ 0x1BD11BDAu;
    uint32_t x0 = c0 + k0, x1 = c1 + k1;
    x0 += x1; x1 = rotl32(x1, 13); x1 ^= x0;
    x0 += x1; x1 = rotl32(x1, 15); x1 ^= x0;
    x0 += x1; x1 = rotl32(x1, 26); x1 ^= x0;
    x0 += x1; x1 = rotl32(x1, 6);  x1 ^= x0;
    x0 += k1; x1 += ks2 + 1u;
    x0 += x1; x1 = rotl32(x1, 17); x1 ^= x0;
    x0 += x1; x1 = rotl32(x1, 29); x1 ^= x0;
    x0 += x1; x1 = rotl32(x1, 16); x1 ^= x0;
    x0 += x1; x1 = rotl32(x1, 24); x1 ^= x0;
    x0 += ks2; x1 += k0 + 2u;
    x0 += x1; x1 = rotl32(x1, 13); x1 ^= x0;
    x0 += x1; x1 = rotl32(x1, 15); x1 ^= x0;
    x0 += x1; x1 = rotl32(x1, 26); x1 ^= x0;
    x0 += x1; x1 = rotl32(x1, 6);  x1 ^= x0;
    x0 += k0; x1 += k1 + 3u;
    x0 += x1; x1 = rotl32(x1, 17); x1 ^= x0;
    x0 += x1; x1 = rotl32(x1, 29); x1 ^= x0;
    x0 += x1; x1 = rotl32(x1, 16); x1 ^= x0;
    x0 += x1; x1 = rotl32(x1, 24); x1 ^= x0;
    x0 += k1; x1 += ks2 + 4u;
    x0 += x1; x1 = rotl32(x1, 13); x1 ^= x0;
    x0 += x1; x1 = rotl32(x1, 15); x1 ^= x0;
    x0 += x1; x1 = rotl32(x1, 26); x1 ^= x0;
    x0 += x1; x1 = rotl32(x1, 6);  x1 ^= x0;
    x0 += ks2; x1 += k0 + 5u;
    o0 = x0; o1 = x1;
}

__device__ __forceinline__ bool dropout_keep(uint32_t i) {
    uint32_t o0, o1;
    threefry2x32(0u, 42u, 0u, i, o0, o1);
    return ((o0 ^ o1) & 0x80000000u) == 0u;
}

__device__ __forceinline__ uint32_t bf16_rne(float f) {   // fp32 -> bf16 bits (RNE)
    uint32_t u = __float_as_uint(f);
    return (u + 0x7FFFu + ((u >> 16) & 1u)) >> 16;
}

__device__ __forceinline__ uint32_t cvt_pk_bf16(float lo, float hi) {
    uint32_t r;
    asm("v_cvt_pk_bf16_f32 %0, %1, %2" : "=v"(r) : "v"(lo), "v"(hi));
    return r;   // RNE, bit-identical to bf16_rne pair
}

// FUSED build: blocks 0..15 = W transpose to bf16 wt[n][k]; blocks 16.. =
// bucket scatter. ONE f64 atomic per edge: old high bits = bucket slot;
// fraction accumulates weighted degree. 4B records: (row<<16)|fp16(ew).
__global__ __launch_bounds__(256) void k_build(const float* __restrict__ W,
                                               ushort* __restrict__ wt,
                                               const int* __restrict__ ei,
                                               const float* __restrict__ ew,
                                               double* __restrict__ degsum,
                                               uint32_t* __restrict__ bucket) {
    int t = threadIdx.x;
    if (blockIdx.x < 16) {
        __shared__ float td[64][65];
        int kb = blockIdx.x & 3, nb = blockIdx.x >> 2;   // 4x4 tiles of 64x64
        int nl = t & 63, r4 = t >> 6;
#pragma unroll
        for (int i = 0; i < 16; i++) {
            int kl = r4 + 4 * i;
            td[kl][nl] = W[(size_t)(kb * 64 + kl) * 256 + nb * 64 + nl];
        }
        __syncthreads();
        int kp = t & 31, nl2 = t >> 5;
        uint32_t* wt32 = (uint32_t*)wt;
#pragma unroll
        for (int i = 0; i < 8; i++) {
            int n = nl2 + 8 * i;
            uint32_t p = bf16_rne(td[2 * kp][n]) | (bf16_rne(td[2 * kp + 1][n]) << 16);
            wt32[((size_t)(nb * 64 + n) * 256 + kb * 64 + 2 * kp) >> 1] = p;
        }
    } else {
        int e = (blockIdx.x - 16) * 256 + t;   // exactly 800000 threads
        int r = ei[e];
        int c = ei[N_EDGES + e];
        float w = ew[e];
        double old = atomicAdd(&degsum[c], 4294967296.0 + (double)w);
        int pos = (int)(old * (1.0 / 4294967296.0));     // prior count = slot
        __half hw = __float2half(w);
        bucket[(size_t)c * BCAP + pos] =
            ((uint32_t)r << 16) | (uint32_t)__half_as_ushort(hw);
    }
}

// ---------------- MFMA GEMM: h'(fp8 e4m3) = dinv[row] * (x @ W1) -----------
// Prologue derives dinv/cnt for this block's 64 rows from degsum (publishes
// them for k_agg) — k_dinv kernel deleted. Blocks 0..127 also zero sums.
__device__ __forceinline__ int swz(int row, int kByte) {
    return (row << 9) + (kByte ^ ((row & 7) << 4));
}

__global__ __launch_bounds__(256) void k_gemm(const float* __restrict__ x,
                                              const ushort* __restrict__ wt,
                                              const double* __restrict__ degsum,
                                              float* __restrict__ dinv,
                                              int* __restrict__ cnt,
                                              float* __restrict__ sums,
                                              uint8_t* __restrict__ hb) {
    __shared__ __align__(16) char smem[73728];   // A:[0,32K) Bt:[32K,64K) C:[64K,72K)
    __shared__ float sdinv[64];
    int tid = threadIdx.x;
    int Mbase = blockIdx.x * 64;

    if (blockIdx.x < 128) sums[blockIdx.x * 256 + tid] = 0.0f;
    if (tid < 64) {
        int node = Mbase + tid;
        if (node < N_NODES) {
            double val = degsum[node];
            int c = (int)(val * (1.0 / 4294967296.0));    // exact
            float deg = (float)(val - (double)c * 4294967296.0) + 1.0f;
            float di = rsqrtf(deg);                        // deg >= 1 always
            sdinv[tid] = di;
            dinv[node] = di;
            cnt[node] = c;
        } else {
            sdinv[tid] = 0.0f;
        }
    }
    // stage A: x[Mbase..+63][0..255] -> bf16 via v_cvt_pk_bf16_f32, swizzled
    const float4* xv = (const float4*)x;
#pragma unroll
    for (int i = 0; i < 16; i++) {
        int f = tid + i * 256;        // flat float4 id, 0..4095
        int r = f >> 6;               // row 0..63
        int c4 = f & 63;              // float4 index -> k = 4*c4
        int node = Mbase + r; if (node >= N_NODES) node = N_NODES - 1;
        float4 v = xv[(size_t)node * 64 + c4];
        uint32_t p0 = cvt_pk_bf16(v.x, v.y);
        uint32_t p1 = cvt_pk_bf16(v.z, v.w);
        *(uint2*)(smem + swz(r, c4 * 8)) = make_uint2(p0, p1);
    }

    int l = tid & 63;
    int w = tid >> 6;
    int wr = w >> 1, wc = w & 1;          // wave grid 2x2, each 32x32
    int lr = l & 15;
    int kg = l >> 4;
    int drow = (l >> 4) * 4;
    int dcol = l & 15;
    const uint4* wt4 = (const uint4*)wt;  // 16B units; 32 per 512B row
    ushort* c_lds = (ushort*)(smem + 65536);   // [64][64] fp16 tile

    for (int nb = 0; nb < 4; nb++) {
        // stage Bt tile: wt rows nb*64..+63 (coalesced uint4 copy)
#pragma unroll
        for (int i = 0; i < 8; i++) {
            int f = tid + i * 256;    // 0..2047 uint4
            int r = f >> 5;           // row 0..63
            int c = f & 31;           // 16B chunk
            uint4 v = wt4[(size_t)(nb * 64 + r) * 32 + c];
            *(uint4*)(smem + 32768 + swz(r, c * 16)) = v;
        }
        __syncthreads();              // Bt ready; prev copy-out done

        f32x4 acc00 = {0.f, 0.f, 0.f, 0.f};
        f32x4 acc01 = acc00, acc10 = acc00, acc11 = acc00;
#pragma unroll
        for (int ks = 0; ks < 8; ks++) {
            int kB = ks * 64 + kg * 16;
            bf16x8 a0 = *(const bf16x8*)(smem + swz(wr * 32 + lr, kB));
            bf16x8 a1 = *(const bf16x8*)(smem + swz(wr * 32 + 16 + lr, kB));
            bf16x8 b0 = *(const bf16x8*)(smem + 32768 + swz(wc * 32 + lr, kB));
            bf16x8 b1 = *(const bf16x8*)(smem + 32768 + swz(wc * 32 + 16 + lr, kB));
            acc00 = __builtin_amdgcn_mfma_f32_16x16x32_bf16(a0, b0, acc00, 0, 0, 0);
            acc01 = __builtin_amdgcn_mfma_f32_16x16x32_bf16(a0, b1, acc01, 0, 0, 0);
            acc10 = __builtin_amdgcn_mfma_f32_16x16x32_bf16(a1, b0, acc10, 0, 0, 0);
            acc11 = __builtin_amdgcn_mfma_f32_16x16x32_bf16(a1, b1, acc11, 0, 0, 0);
        }
        // D layout row=(l>>4)*4+r, col=l&15 (m89); scale by dinv; fp16 C_lds
#pragma unroll
        for (int r = 0; r < 4; r++) {
            int lr0 = wr * 32 + drow + r;
            float s0 = sdinv[lr0], s1 = sdinv[lr0 + 16];
            int cc = wc * 32 + dcol;
            __half h00 = __float2half(acc00[r] * s0);
            __half h01 = __float2half(acc01[r] * s0);
            __half h10 = __float2half(acc10[r] * s1);
            __half h11 = __float2half(acc11[r] * s1);
            c_lds[lr0 * 64 + cc]             = *(ushort*)&h00;
            c_lds[lr0 * 64 + cc + 16]        = *(ushort*)&h01;
            c_lds[(lr0 + 16) * 64 + cc]      = *(ushort*)&h10;
            c_lds[(lr0 + 16) * 64 + cc + 16] = *(ushort*)&h11;
        }
        __syncthreads();              // C_lds complete
        // copy-out with fp16->fp8 convert: 512 uint2 (4KB), 2/thread
#pragma unroll
        for (int i = 0; i < 2; i++) {
            int idx = tid + i * 256;  // 0..511
            int r = idx >> 3;         // row 0..63
            int c8 = idx & 7;         // 8-col group
            uint4 v = ((const uint4*)c_lds)[idx];   // 8 fp16
            __half2* hp = (__half2*)&v;
            float f0 = __low2float(hp[0]), f1 = __high2float(hp[0]);
            float f2 = __low2float(hp[1]), f3 = __high2float(hp[1]);
            float f4 = __low2float(hp[2]), f5 = __high2float(hp[2]);
            float f6 = __low2float(hp[3]), f7 = __high2float(hp[3]);
            uint32_t w0 = __builtin_amdgcn_cvt_pk_fp8_f32(f0, f1, 0, false);
            w0 = __builtin_amdgcn_cvt_pk_fp8_f32(f2, f3, w0, true);
            uint32_t w1 = __builtin_amdgcn_cvt_pk_fp8_f32(f4, f5, 0, false);
            w1 = __builtin_amdgcn_cvt_pk_fp8_f32(f6, f7, w1, true);
            int node = Mbase + r;
            if (node < N_NODES)
                *(uint2*)(hb + (size_t)node * 256 + nb * 64 + c8 * 8) =
                    make_uint2(w0, w1);
        }
    }
}

// Bucket aggregate (fp8 h, f32 accum): s = n*BCAP, e = s + cnt[n].
// 4B records: row = rec>>16, w = fp16(rec&0xFFFF). Unguarded prefetch
// (bucket padded); tail reloads clamped (poison-safe). Inline threefry;
// block-level LDS pool flush.
__device__ __forceinline__ void fma8f(float* a, uint2 u, float w) {
    f32x2 p0 = __builtin_amdgcn_cvt_pk_f32_fp8(u.x, false);
    f32x2 p1 = __builtin_amdgcn_cvt_pk_f32_fp8(u.x, true);
    f32x2 p2 = __builtin_amdgcn_cvt_pk_f32_fp8(u.y, false);
    f32x2 p3 = __builtin_amdgcn_cvt_pk_f32_fp8(u.y, true);
    a[0] = fmaf(w, p0.x, a[0]); a[1] = fmaf(w, p0.y, a[1]);
    a[2] = fmaf(w, p1.x, a[2]); a[3] = fmaf(w, p1.y, a[3]);
    a[4] = fmaf(w, p2.x, a[4]); a[5] = fmaf(w, p2.y, a[5]);
    a[6] = fmaf(w, p3.x, a[6]); a[7] = fmaf(w, p3.y, a[7]);
}

__device__ __forceinline__ float rec_w(uint32_t rec) {
    __half h = __ushort_as_half((ushort)(rec & 0xFFFFu));
    return __half2float(h);
}

__global__ __launch_bounds__(256) void k_agg(const int* __restrict__ cnt,
                                             const uint32_t* __restrict__ bucket,
                                             const uint8_t* __restrict__ hb,
                                             const float* __restrict__ dinv,
                                             const float* __restrict__ b1,
                                             const int* __restrict__ gidx,
                                             float* __restrict__ sums) {
    __shared__ float ls[4][256];
    int wid = threadIdx.x >> 6;
    int l = threadIdx.x & 63;
    int half = l >> 5;                     // 0: even edge slots, 1: odd
    int cl = l & 31;                       // 8B column chunk (cols 8cl..8cl+7)
    int n = blockIdx.x * 4 + wid;          // always < N_NODES
    const uint2* h8 = (const uint2*)hb;    // 32 uint2 per 256B row
    int cn = cnt[n];
    int s = n * BCAP;
    int e = s + cn;
    int last = e - 1;

    // independent loads issued early
    uint2 un = h8[(size_t)n * 32 + cl];
    float4 bv = ((const float4*)b1)[2 * cl + half];
    float dn = dinv[n];
    int gfirst = gidx[blockIdx.x * 4];
    int glast  = gidx[blockIdx.x * 4 + 3];

    int off = 4 * half;
    int col = 8 * cl + off;

    // first batch preload (unguarded within padded bucket array)
    int j = s;
    uint32_t E0, E1, E2, E3;
    if (j < e) {
        int i0 = j + half;
        E0 = bucket[i0];
        E1 = bucket[i0 + 2];
        E2 = bucket[i0 + 4];
        E3 = bucket[i0 + 6];
    }

    // dropout factors: threefry VALU hidden under the in-flight loads
    uint32_t base = (uint32_t)n * D + (uint32_t)col;
    float m0 = dropout_keep(base + 0u) ? 2.f : 0.f;
    float m1 = dropout_keep(base + 1u) ? 2.f : 0.f;
    float m2 = dropout_keep(base + 2u) ? 2.f : 0.f;
    float m3 = dropout_keep(base + 3u) ? 2.f : 0.f;

    float A0[8] = {0,0,0,0,0,0,0,0}, A1[8] = {0,0,0,0,0,0,0,0};

    // -------- main loop: batch fully valid, no clamps/selects --------
    for (; j + 8 <= e; j += 8) {
        uint2 u0 = h8[(size_t)(uint32_t)(((E0 >> 16) << 5) + cl)];
        uint2 u1 = h8[(size_t)(uint32_t)(((E1 >> 16) << 5) + cl)];
        uint2 u2 = h8[(size_t)(uint32_t)(((E2 >> 16) << 5) + cl)];
        uint2 u3 = h8[(size_t)(uint32_t)(((E3 >> 16) << 5) + cl)];
        float w0 = rec_w(E0);
        float w1 = rec_w(E1);
        float w2 = rec_w(E2);
        float w3 = rec_w(E3);
        // unguarded prefetch (padded bucket array)
        int i0n = j + 8 + half;
        E0 = bucket[i0n];
        E1 = bucket[i0n + 2];
        E2 = bucket[i0n + 4];
        E3 = bucket[i0n + 6];
        fma8f(A0, u0, w0); fma8f(A1, u1, w1);
        fma8f(A0, u2, w2); fma8f(A1, u3, w3);
    }
    // -------- tail: RELOAD with clamped slot indices (poison-safe) --------
    if (j < e) {
        int x0 = j + half, x1 = x0 + 2, x2 = x0 + 4, x3 = x0 + 6;
        int c0 = x0 < last ? x0 : last;
        int c1 = x1 < last ? x1 : last;
        int c2 = x2 < last ? x2 : last;
        int c3 = x3 < last ? x3 : last;
        uint32_t F0 = bucket[c0], F1 = bucket[c1];
        uint32_t F2 = bucket[c2], F3 = bucket[c3];
        uint2 u0 = h8[(size_t)(uint32_t)(((F0 >> 16) << 5) + cl)];
        uint2 u1 = h8[(size_t)(uint32_t)(((F1 >> 16) << 5) + cl)];
        uint2 u2 = h8[(size_t)(uint32_t)(((F2 >> 16) << 5) + cl)];
        uint2 u3 = h8[(size_t)(uint32_t)(((F3 >> 16) << 5) + cl)];
        float w0 = x0 <= last ? rec_w(F0) : 0.f;
        float w1 = x1 <= last ? rec_w(F1) : 0.f;
        float w2 = x2 <= last ? rec_w(F2) : 0.f;
        float w3 = x3 <= last ? rec_w(F3) : 0.f;
        fma8f(A0, u0, w0); fma8f(A1, u1, w1);
        fma8f(A0, u2, w2); fma8f(A1, u3, w3);
    }

    float full[8];
#pragma unroll
    for (int k = 0; k < 8; k++)
        full[k] = A0[k] + A1[k];
#pragma unroll
    for (int k = 0; k < 8; k++)
        full[k] += __shfl_xor(full[k], 32, 64);   // combine the two edge-halves

    // self-loop + bias + relu + dropout for this lane's 4 cols
    uint32_t word = half ? un.y : un.x;
    f32x2 q0 = __builtin_amdgcn_cvt_pk_f32_fp8(word, false);
    f32x2 q1 = __builtin_amdgcn_cvt_pk_f32_fp8(word, true);
    float v0 = fmaxf(dn * (full[off + 0] + q0.x) + bv.x, 0.f) * m0;
    float v1 = fmaxf(dn * (full[off + 1] + q0.y) + bv.y, 0.f) * m1;
    float v2 = fmaxf(dn * (full[off + 2] + q1.x) + bv.z, 0.f) * m2;
    float v3 = fmaxf(dn * (full[off + 3] + q1.y) + bv.w, 0.f) * m3;

    if (gfirst == glast) {                 // block-uniform branch (~99% of blocks)
        *(float4*)&ls[wid][col] = make_float4(v0, v1, v2, v3);
        __syncthreads();
        int t = threadIdx.x;
        float sv = (ls[0][t] + ls[1][t]) + (ls[2][t] + ls[3][t]);
        atomicAdd(&sums[(size_t)gfirst * D + t], sv);
    } else {                               // graph boundary inside block (rare)
        int g = gidx[n];
        float* sg = &sums[(size_t)g * D + col];
        atomicAdd(sg + 0, v0);
        atomicAdd(sg + 1, v1);
        atomicAdd(sg + 2, v2);
        atomicAdd(sg + 3, v3);
    }
}

// pooled = sums/cnt (cnt via binary search on sorted gidx); out = pooled@fcW+fcb
__global__ __launch_bounds__(256) void k_out(const float* __restrict__ sums,
                                             const int* __restrict__ gidx,
                                             const float* __restrict__ fcW,
                                             const float* __restrict__ fcb,
                                             float* __restrict__ out) {
    __shared__ int sh[2];
    __shared__ float p[D];
    int g = blockIdx.x, t = threadIdx.x;
    if (t == 0) {
        int lo = 0, hi = N_NODES;
        while (lo < hi) { int m = (lo + hi) >> 1; if (gidx[m] < g) lo = m + 1; else hi = m; }
        sh[0] = lo;
        int lo2 = lo; hi = N_NODES;
        while (lo2 < hi) { int m = (lo2 + hi) >> 1; if (gidx[m] < g + 1) lo2 = m + 1; else hi = m; }
        sh[1] = lo2;
    }
    __syncthreads();
    float c = fmaxf((float)(sh[1] - sh[0]), 1.0f);
    p[t] = sums[(size_t)g * D + t] / c;
    __syncthreads();
    if (t < D_OUT) {
        float acc = fcb[t];
        for (int k = 0; k < D; k++)
            acc = fmaf(p[k], fcW[k * D_OUT + t], acc);
        out[g * D_OUT + t] = acc;
    }
}

extern "C" void kernel_launch(void* const* d_in, const int* in_sizes, int n_in,
                              void* d_out, int out_size, void* d_ws, size_t ws_size,
                              hipStream_t stream) {
    const float* x   = (const float*)d_in[0];
    const int*   ei  = (const int*)d_in[1];
    const float* ew  = (const float*)d_in[2];
    const int*   gix = (const int*)d_in[3];
    const float* W1  = (const float*)d_in[4];
    const float* b1  = (const float*)d_in[5];
    const float* fcW = (const float*)d_in[6];
    const float* fcb = (const float*)d_in[7];
    float* out = (float*)d_out;

    float*    ws     = (float*)d_ws;
    float*    dinv   = ws;                                     //     65,536 f
    uint8_t*  hb     = (uint8_t*)(ws + 65536);                 //  12.8 MB fp8
    uint32_t* bucket = (uint32_t*)(ws + 65536 + 3200000);      //  50000*64 u32 = 12.8MB
    int*      cnt    = (int*)(bucket + (size_t)N_NODES * BCAP + 16);  // 65,536 (+pad)
    ushort*   wt     = (ushort*)(cnt + 65536);                 //     65,536 us
    float*    sums   = (float*)(wt + 65536);                   //     32,768 f
    double*   degsum = (double*)(sums + 32768);                //     50,000 f64
    // total ~27 MB

    // per-call zero-init (replays don't re-poison)
    hipMemsetAsync(degsum, 0, N_NODES * sizeof(double), stream);

    k_build<<<16 + FILL_NB, 256, 0, stream>>>(W1, wt, ei, ew, degsum, bucket);
    k_gemm<<<(N_NODES + 63) / 64, 256, 0, stream>>>(x, wt, degsum, dinv, cnt, sums, hb);
    k_agg<<<N_NODES / 4, 256, 0, stream>>>(cnt, bucket, hb, dinv, b1, gix, sums);
    k_out<<<N_GRAPHS, 256, 0, stream>>>(sums, gix, fcW, fcb, out);
}

// Round 22
// 156.388 us; speedup vs baseline: 1.2627x; 1.0009x over previous
//
#include <hip/hip_runtime.h>
#include <hip/hip_fp16.h>
#include <stdint.h>

// Problem constants (match reference)
#define N_NODES  50000
#define N_EDGES  800000
#define D        256
#define D_OUT    16
#define N_GRAPHS 128
#define FILL_NB  3125       // N_EDGES/256
#define BCAP     64         // bucket capacity; Poisson(16) max deg ~45 over 50k

// JAX jax_threefry_partitionable=True: bits32(i) = fold(threefry2x32((0,42),(0,i))),
// fold = o0 ^ o1; keep iff top bit == 0.  (verified round 2, absmax 0.0)
// r20/21 lesson: build is TCC-atomic-THROUGHPUT bound (record width change
// was null). r22: atomic reduced to bare u32 counter; weighted degree is
// recomputed in gemm's prologue by scanning the node's own bucket records.

typedef short bf16x8 __attribute__((ext_vector_type(8)));
typedef float f32x4  __attribute__((ext_vector_type(4)));
typedef float f32x2  __attribute__((ext_vector_type(2)));

__device__ __forceinline__ uint32_t rotl32(uint32_t x, int d) {
    return (x << d) | (x >> (32 - d));
}

__device__ __forceinline__ void threefry2x32(uint32_t k0, uint32_t k1,
                                             uint32_t c0, uint32_t c1,
                                             uint32_t& o0, uint32_t& o1) {
    uint32_t ks2 = k0 ^ k1 ^ 0x1BD11BDAu;
    uint32_t x0 = c0 + k0, x1 = c1 + k1;
    x0 += x1; x1 = rotl32(x1, 13); x1 ^= x0;
    x0 += x1; x1 = rotl32(x1, 15); x1 ^= x0;
    x0 += x1; x1 = rotl32(x1, 26); x1 ^= x0;
    x0 += x1; x1 = rotl32(x1, 6);  x1 ^= x0;
    x0 += k1; x1 += ks2 + 1u;
    x0 += x1; x1 = rotl32(x1, 17); x1 ^= x0;
    x0 += x1; x1 = rotl32(x1, 29); x1 ^= x0;
    x0 += x1; x1 = rotl32(x1, 16); x1 ^= x0;
    x0 += x1; x1 = rotl32(x1, 24); x1 ^= x0;
    x0 += ks2; x1 += k0 + 2u;
    x0 += x1; x1 = rotl32(x1, 13); x1 ^= x0;
    x0 += x1; x1 = rotl32(x1, 15); x1 ^= x0;
    x0 += x1; x1 = rotl32(x1, 26); x1 ^= x0;
    x0 += x1; x1 = rotl32(x1, 6);  x1 ^= x0;
    x0 += k0; x1 += k1 + 3u;
    x0 += x1; x1 = rotl32(x1, 17); x1 ^= x0;
    x0 += x1; x1 = rotl32(x1, 29); x1 ^= x0;
    x0 += x1; x1 = rotl32(x1, 16); x1 ^= x0;
    x0 += x1; x1 = rotl32(x1, 24); x1 ^= x0;
    x0 += k1; x1 += ks2 + 4u;
    x0 += x1; x1 = rotl32(x1, 13); x1 ^= x0;
    x0 += x1; x1 = rotl32(x1, 15); x1 ^= x0;
    x0 += x1; x1 = rotl32(x1, 26); x1 ^= x0;
    x0 += x1; x1 = rotl32(x1, 6);  x1 ^= x0;
    x0 += ks2; x1 += k0 + 5u;
    o0 = x0; o1 = x1;
}

__device__ __forceinline__ bool dropout_keep(uint32_t i) {
    uint32_t o0, o1;
    threefry2x32(0u, 42u, 0u, i, o0, o1);
    return ((o0 ^ o1) & 0x80000000u) == 0u;
}

__device__ __forceinline__ uint32_t bf16_rne(float f) {   // fp32 -> bf16 bits (RNE)
    uint32_t u = __float_as_uint(f);
    return (u + 0x7FFFu + ((u >> 16) & 1u)) >> 16;
}

__device__ __forceinline__ uint32_t cvt_pk_bf16(float lo, float hi) {
    uint32_t r;
    asm("v_cvt_pk_bf16_f32 %0, %1, %2" : "=v"(r) : "v"(lo), "v"(hi));
    return r;   // RNE, bit-identical to bf16_rne pair
}

// FUSED build: blocks 0..15 = W transpose to bf16 wt[n][k]; blocks 16.. =
// bucket scatter with a BARE u32 counter atomic (cnt pre-zeroed by memset).
// Records: (row<<16) | fp16(ew).
__global__ __launch_bounds__(256) void k_build(const float* __restrict__ W,
                                               ushort* __restrict__ wt,
                                               const int* __restrict__ ei,
                                               const float* __restrict__ ew,
                                               uint32_t* __restrict__ cnt,
                                               uint32_t* __restrict__ bucket) {
    int t = threadIdx.x;
    if (blockIdx.x < 16) {
        __shared__ float td[64][65];
        int kb = blockIdx.x & 3, nb = blockIdx.x >> 2;   // 4x4 tiles of 64x64
        int nl = t & 63, r4 = t >> 6;
#pragma unroll
        for (int i = 0; i < 16; i++) {
            int kl = r4 + 4 * i;
            td[kl][nl] = W[(size_t)(kb * 64 + kl) * 256 + nb * 64 + nl];
        }
        __syncthreads();
        int kp = t & 31, nl2 = t >> 5;
        uint32_t* wt32 = (uint32_t*)wt;
#pragma unroll
        for (int i = 0; i < 8; i++) {
            int n = nl2 + 8 * i;
            uint32_t p = bf16_rne(td[2 * kp][n]) | (bf16_rne(td[2 * kp + 1][n]) << 16);
            wt32[((size_t)(nb * 64 + n) * 256 + kb * 64 + 2 * kp) >> 1] = p;
        }
    } else {
        int e = (blockIdx.x - 16) * 256 + t;   // exactly 800000 threads
        int r = ei[e];
        int c = ei[N_EDGES + e];
        float w = ew[e];
        uint32_t pos = atomicAdd(&cnt[c], 1u);
        __half hw = __float2half(w);
        bucket[(size_t)c * BCAP + pos] =
            ((uint32_t)r << 16) | (uint32_t)__half_as_ushort(hw);
    }
}

// ---------------- MFMA GEMM: h'(fp8 e4m3) = dinv[row] * (x @ W1) -----------
// Prologue: deg = 1 + sum of this block's 64 nodes' record weights (4 threads
// per node scan the bucket), dinv derived + published for k_agg. Blocks
// 0..127 also zero sums. No degsum buffer anywhere.
__device__ __forceinline__ int swz(int row, int kByte) {
    return (row << 9) + (kByte ^ ((row & 7) << 4));
}

__global__ __launch_bounds__(256) void k_gemm(const float* __restrict__ x,
                                              const ushort* __restrict__ wt,
                                              const uint32_t* __restrict__ cnt,
                                              const uint32_t* __restrict__ bucket,
                                              float* __restrict__ dinv,
                                              float* __restrict__ sums,
                                              uint8_t* __restrict__ hb) {
    __shared__ __align__(16) char smem[73728];   // A:[0,32K) Bt:[32K,64K) C:[64K,72K)
    __shared__ float sdinv[64];
    __shared__ float partsum[256];
    int tid = threadIdx.x;
    int Mbase = blockIdx.x * 64;

    if (blockIdx.x < 128) sums[blockIdx.x * 256 + tid] = 0.0f;

    // ---- prologue: weighted degree from bucket records (4 threads/node) ----
    {
        int node = Mbase + (tid & 63);
        int q = tid >> 6;                 // quarter 0..3 (16 slots each)
        float psum = 0.f;
        if (node < N_NODES) {
            int cn = (int)cnt[node];
            int lo = q * 16;
            int hi = cn < lo + 16 ? cn : lo + 16;
            const uint32_t* bp = bucket + (size_t)node * BCAP;
            for (int i = lo; i < hi; i++)
                psum += __half2float(__ushort_as_half((ushort)(bp[i] & 0xFFFFu)));
        }
        partsum[tid] = psum;
    }
    __syncthreads();
    if (tid < 64) {
        int node = Mbase + tid;
        float deg = 1.0f + ((partsum[tid] + partsum[tid + 64]) +
                            (partsum[tid + 128] + partsum[tid + 192]));
        float di = rsqrtf(deg);
        sdinv[tid] = di;
        if (node < N_NODES) dinv[node] = di;
    }

    // stage A: x[Mbase..+63][0..255] -> bf16 via v_cvt_pk_bf16_f32, swizzled
    const float4* xv = (const float4*)x;
#pragma unroll
    for (int i = 0; i < 16; i++) {
        int f = tid + i * 256;        // flat float4 id, 0..4095
        int r = f >> 6;               // row 0..63
        int c4 = f & 63;              // float4 index -> k = 4*c4
        int node = Mbase + r; if (node >= N_NODES) node = N_NODES - 1;
        float4 v = xv[(size_t)node * 64 + c4];
        uint32_t p0 = cvt_pk_bf16(v.x, v.y);
        uint32_t p1 = cvt_pk_bf16(v.z, v.w);
        *(uint2*)(smem + swz(r, c4 * 8)) = make_uint2(p0, p1);
    }

    int l = tid & 63;
    int w = tid >> 6;
    int wr = w >> 1, wc = w & 1;          // wave grid 2x2, each 32x32
    int lr = l & 15;
    int kg = l >> 4;
    int drow = (l >> 4) * 4;
    int dcol = l & 15;
    const uint4* wt4 = (const uint4*)wt;  // 16B units; 32 per 512B row
    ushort* c_lds = (ushort*)(smem + 65536);   // [64][64] fp16 tile

    for (int nb = 0; nb < 4; nb++) {
        // stage Bt tile: wt rows nb*64..+63 (coalesced uint4 copy)
#pragma unroll
        for (int i = 0; i < 8; i++) {
            int f = tid + i * 256;    // 0..2047 uint4
            int r = f >> 5;           // row 0..63
            int c = f & 31;           // 16B chunk
            uint4 v = wt4[(size_t)(nb * 64 + r) * 32 + c];
            *(uint4*)(smem + 32768 + swz(r, c * 16)) = v;
        }
        __syncthreads();              // Bt + sdinv ready; prev copy-out done

        f32x4 acc00 = {0.f, 0.f, 0.f, 0.f};
        f32x4 acc01 = acc00, acc10 = acc00, acc11 = acc00;
#pragma unroll
        for (int ks = 0; ks < 8; ks++) {
            int kB = ks * 64 + kg * 16;
            bf16x8 a0 = *(const bf16x8*)(smem + swz(wr * 32 + lr, kB));
            bf16x8 a1 = *(const bf16x8*)(smem + swz(wr * 32 + 16 + lr, kB));
            bf16x8 b0 = *(const bf16x8*)(smem + 32768 + swz(wc * 32 + lr, kB));
            bf16x8 b1 = *(const bf16x8*)(smem + 32768 + swz(wc * 32 + 16 + lr, kB));
            acc00 = __builtin_amdgcn_mfma_f32_16x16x32_bf16(a0, b0, acc00, 0, 0, 0);
            acc01 = __builtin_amdgcn_mfma_f32_16x16x32_bf16(a0, b1, acc01, 0, 0, 0);
            acc10 = __builtin_amdgcn_mfma_f32_16x16x32_bf16(a1, b0, acc10, 0, 0, 0);
            acc11 = __builtin_amdgcn_mfma_f32_16x16x32_bf16(a1, b1, acc11, 0, 0, 0);
        }
        // D layout row=(l>>4)*4+r, col=l&15 (m89); scale by dinv; fp16 C_lds
#pragma unroll
        for (int r = 0; r < 4; r++) {
            int lr0 = wr * 32 + drow + r;
            float s0 = sdinv[lr0], s1 = sdinv[lr0 + 16];
            int cc = wc * 32 + dcol;
            __half h00 = __float2half(acc00[r] * s0);
            __half h01 = __float2half(acc01[r] * s0);
            __half h10 = __float2half(acc10[r] * s1);
            __half h11 = __float2half(acc11[r] * s1);
            c_lds[lr0 * 64 + cc]             = *(ushort*)&h00;
            c_lds[lr0 * 64 + cc + 16]        = *(ushort*)&h01;
            c_lds[(lr0 + 16) * 64 + cc]      = *(ushort*)&h10;
            c_lds[(lr0 + 16) * 64 + cc + 16] = *(ushort*)&h11;
        }
        __syncthreads();              // C_lds complete
        // copy-out with fp16->fp8 convert: 512 uint2 (4KB), 2/thread
#pragma unroll
        for (int i = 0; i < 2; i++) {
            int idx = tid + i * 256;  // 0..511
            int r = idx >> 3;         // row 0..63
            int c8 = idx & 7;         // 8-col group
            uint4 v = ((const uint4*)c_lds)[idx];   // 8 fp16
            __half2* hp = (__half2*)&v;
            float f0 = __low2float(hp[0]), f1 = __high2float(hp[0]);
            float f2 = __low2float(hp[1]), f3 = __high2float(hp[1]);
            float f4 = __low2float(hp[2]), f5 = __high2float(hp[2]);
            float f6 = __low2float(hp[3]), f7 = __high2float(hp[3]);
            uint32_t w0 = __builtin_amdgcn_cvt_pk_fp8_f32(f0, f1, 0, false);
            w0 = __builtin_amdgcn_cvt_pk_fp8_f32(f2, f3, w0, true);
            uint32_t w1 = __builtin_amdgcn_cvt_pk_fp8_f32(f4, f5, 0, false);
            w1 = __builtin_amdgcn_cvt_pk_fp8_f32(f6, f7, w1, true);
            int node = Mbase + r;
            if (node < N_NODES)
                *(uint2*)(hb + (size_t)node * 256 + nb * 64 + c8 * 8) =
                    make_uint2(w0, w1);
        }
    }
}

// Bucket aggregate (fp8 h, f32 accum): s = n*BCAP, e = s + cnt[n].
// 4B records: row = rec>>16, w = fp16(rec&0xFFFF). Unguarded prefetch
// (bucket padded); tail reloads clamped (poison-safe). Inline threefry;
// block-level LDS pool flush.
__device__ __forceinline__ void fma8f(float* a, uint2 u, float w) {
    f32x2 p0 = __builtin_amdgcn_cvt_pk_f32_fp8(u.x, false);
    f32x2 p1 = __builtin_amdgcn_cvt_pk_f32_fp8(u.x, true);
    f32x2 p2 = __builtin_amdgcn_cvt_pk_f32_fp8(u.y, false);
    f32x2 p3 = __builtin_amdgcn_cvt_pk_f32_fp8(u.y, true);
    a[0] = fmaf(w, p0.x, a[0]); a[1] = fmaf(w, p0.y, a[1]);
    a[2] = fmaf(w, p1.x, a[2]); a[3] = fmaf(w, p1.y, a[3]);
    a[4] = fmaf(w, p2.x, a[4]); a[5] = fmaf(w, p2.y, a[5]);
    a[6] = fmaf(w, p3.x, a[6]); a[7] = fmaf(w, p3.y, a[7]);
}

__device__ __forceinline__ float rec_w(uint32_t rec) {
    __half h = __ushort_as_half((ushort)(rec & 0xFFFFu));
    return __half2float(h);
}

__global__ __launch_bounds__(256) void k_agg(const uint32_t* __restrict__ cnt,
                                             const uint32_t* __restrict__ bucket,
                                             const uint8_t* __restrict__ hb,
                                             const float* __restrict__ dinv,
                                             const float* __restrict__ b1,
                                             const int* __restrict__ gidx,
                                             float* __restrict__ sums) {
    __shared__ float ls[4][256];
    int wid = threadIdx.x >> 6;
    int l = threadIdx.x & 63;
    int half = l >> 5;                     // 0: even edge slots, 1: odd
    int cl = l & 31;                       // 8B column chunk (cols 8cl..8cl+7)
    int n = blockIdx.x * 4 + wid;          // always < N_NODES
    const uint2* h8 = (const uint2*)hb;    // 32 uint2 per 256B row
    int cn = (int)cnt[n];
    int s = n * BCAP;
    int e = s + cn;
    int last = e - 1;

    // independent loads issued early
    uint2 un = h8[(size_t)n * 32 + cl];
    float4 bv = ((const float4*)b1)[2 * cl + half];
    float dn = dinv[n];
    int gfirst = gidx[blockIdx.x * 4];
    int glast  = gidx[blockIdx.x * 4 + 3];

    int off = 4 * half;
    int col = 8 * cl + off;

    // first batch preload (unguarded within padded bucket array)
    int j = s;
    uint32_t E0, E1, E2, E3;
    if (j < e) {
        int i0 = j + half;
        E0 = bucket[i0];
        E1 = bucket[i0 + 2];
        E2 = bucket[i0 + 4];
        E3 = bucket[i0 + 6];
    }

    // dropout factors: threefry VALU hidden under the in-flight loads
    uint32_t base = (uint32_t)n * D + (uint32_t)col;
    float m0 = dropout_keep(base + 0u) ? 2.f : 0.f;
    float m1 = dropout_keep(base + 1u) ? 2.f : 0.f;
    float m2 = dropout_keep(base + 2u) ? 2.f : 0.f;
    float m3 = dropout_keep(base + 3u) ? 2.f : 0.f;

    float A0[8] = {0,0,0,0,0,0,0,0}, A1[8] = {0,0,0,0,0,0,0,0};

    // -------- main loop: batch fully valid, no clamps/selects --------
    for (; j + 8 <= e; j += 8) {
        uint2 u0 = h8[(size_t)(uint32_t)(((E0 >> 16) << 5) + cl)];
        uint2 u1 = h8[(size_t)(uint32_t)(((E1 >> 16) << 5) + cl)];
        uint2 u2 = h8[(size_t)(uint32_t)(((E2 >> 16) << 5) + cl)];
        uint2 u3 = h8[(size_t)(uint32_t)(((E3 >> 16) << 5) + cl)];
        float w0 = rec_w(E0);
        float w1 = rec_w(E1);
        float w2 = rec_w(E2);
        float w3 = rec_w(E3);
        // unguarded prefetch (padded bucket array)
        int i0n = j + 8 + half;
        E0 = bucket[i0n];
        E1 = bucket[i0n + 2];
        E2 = bucket[i0n + 4];
        E3 = bucket[i0n + 6];
        fma8f(A0, u0, w0); fma8f(A1, u1, w1);
        fma8f(A0, u2, w2); fma8f(A1, u3, w3);
    }
    // -------- tail: RELOAD with clamped slot indices (poison-safe) --------
    if (j < e) {
        int x0 = j + half, x1 = x0 + 2, x2 = x0 + 4, x3 = x0 + 6;
        int c0 = x0 < last ? x0 : last;
        int c1 = x1 < last ? x1 : last;
        int c2 = x2 < last ? x2 : last;
        int c3 = x3 < last ? x3 : last;
        uint32_t F0 = bucket[c0], F1 = bucket[c1];
        uint32_t F2 = bucket[c2], F3 = bucket[c3];
        uint2 u0 = h8[(size_t)(uint32_t)(((F0 >> 16) << 5) + cl)];
        uint2 u1 = h8[(size_t)(uint32_t)(((F1 >> 16) << 5) + cl)];
        uint2 u2 = h8[(size_t)(uint32_t)(((F2 >> 16) << 5) + cl)];
        uint2 u3 = h8[(size_t)(uint32_t)(((F3 >> 16) << 5) + cl)];
        float w0 = x0 <= last ? rec_w(F0) : 0.f;
        float w1 = x1 <= last ? rec_w(F1) : 0.f;
        float w2 = x2 <= last ? rec_w(F2) : 0.f;
        float w3 = x3 <= last ? rec_w(F3) : 0.f;
        fma8f(A0, u0, w0); fma8f(A1, u1, w1);
        fma8f(A0, u2, w2); fma8f(A1, u3, w3);
    }

    float full[8];
#pragma unroll
    for (int k = 0; k < 8; k++)
        full[k] = A0[k] + A1[k];
#pragma unroll
    for (int k = 0; k < 8; k++)
        full[k] += __shfl_xor(full[k], 32, 64);   // combine the two edge-halves

    // self-loop + bias + relu + dropout for this lane's 4 cols
    uint32_t word = half ? un.y : un.x;
    f32x2 q0 = __builtin_amdgcn_cvt_pk_f32_fp8(word, false);
    f32x2 q1 = __builtin_amdgcn_cvt_pk_f32_fp8(word, true);
    float v0 = fmaxf(dn * (full[off + 0] + q0.x) + bv.x, 0.f) * m0;
    float v1 = fmaxf(dn * (full[off + 1] + q0.y) + bv.y, 0.f) * m1;
    float v2 = fmaxf(dn * (full[off + 2] + q1.x) + bv.z, 0.f) * m2;
    float v3 = fmaxf(dn * (full[off + 3] + q1.y) + bv.w, 0.f) * m3;

    if (gfirst == glast) {                 // block-uniform branch (~99% of blocks)
        *(float4*)&ls[wid][col] = make_float4(v0, v1, v2, v3);
        __syncthreads();
        int t = threadIdx.x;
        float sv = (ls[0][t] + ls[1][t]) + (ls[2][t] + ls[3][t]);
        atomicAdd(&sums[(size_t)gfirst * D + t], sv);
    } else {                               // graph boundary inside block (rare)
        int g = gidx[n];
        float* sg = &sums[(size_t)g * D + col];
        atomicAdd(sg + 0, v0);
        atomicAdd(sg + 1, v1);
        atomicAdd(sg + 2, v2);
        atomicAdd(sg + 3, v3);
    }
}

// pooled = sums/cnt (cnt via binary search on sorted gidx); out = pooled@fcW+fcb
__global__ __launch_bounds__(256) void k_out(const float* __restrict__ sums,
                                             const int* __restrict__ gidx,
                                             const float* __restrict__ fcW,
                                             const float* __restrict__ fcb,
                                             float* __restrict__ out) {
    __shared__ int sh[2];
    __shared__ float p[D];
    int g = blockIdx.x, t = threadIdx.x;
    if (t == 0) {
        int lo = 0, hi = N_NODES;
        while (lo < hi) { int m = (lo + hi) >> 1; if (gidx[m] < g) lo = m + 1; else hi = m; }
        sh[0] = lo;
        int lo2 = lo; hi = N_NODES;
        while (lo2 < hi) { int m = (lo2 + hi) >> 1; if (gidx[m] < g + 1) lo2 = m + 1; else hi = m; }
        sh[1] = lo2;
    }
    __syncthreads();
    float c = fmaxf((float)(sh[1] - sh[0]), 1.0f);
    p[t] = sums[(size_t)g * D + t] / c;
    __syncthreads();
    if (t < D_OUT) {
        float acc = fcb[t];
        for (int k = 0; k < D; k++)
            acc = fmaf(p[k], fcW[k * D_OUT + t], acc);
        out[g * D_OUT + t] = acc;
    }
}

extern "C" void kernel_launch(void* const* d_in, const int* in_sizes, int n_in,
                              void* d_out, int out_size, void* d_ws, size_t ws_size,
                              hipStream_t stream) {
    const float* x   = (const float*)d_in[0];
    const int*   ei  = (const int*)d_in[1];
    const float* ew  = (const float*)d_in[2];
    const int*   gix = (const int*)d_in[3];
    const float* W1  = (const float*)d_in[4];
    const float* b1  = (const float*)d_in[5];
    const float* fcW = (const float*)d_in[6];
    const float* fcb = (const float*)d_in[7];
    float* out = (float*)d_out;

    float*    ws     = (float*)d_ws;
    float*    dinv   = ws;                                     //     65,536 f
    uint8_t*  hb     = (uint8_t*)(ws + 65536);                 //  12.8 MB fp8
    uint32_t* bucket = (uint32_t*)(ws + 65536 + 3200000);      //  50000*64 u32 = 12.8MB
    uint32_t* cnt    = bucket + (size_t)N_NODES * BCAP + 16;   //  50,000 u32 (+pad)
    ushort*   wt     = (ushort*)(cnt + 65536);                 //     65,536 us
    float*    sums   = (float*)(wt + 65536);                   //     32,768 f
    // total ~27 MB

    // per-call zero-init (replays don't re-poison)
    hipMemsetAsync(cnt, 0, N_NODES * sizeof(uint32_t), stream);

    k_build<<<16 + FILL_NB, 256, 0, stream>>>(W1, wt, ei, ew, cnt, bucket);
    k_gemm<<<(N_NODES + 63) / 64, 256, 0, stream>>>(x, wt, cnt, bucket, dinv, sums, hb);
    k_agg<<<N_NODES / 4, 256, 0, stream>>>(cnt, bucket, hb, dinv, b1, gix, sums);
    k_out<<<N_GRAPHS, 256, 0, stream>>>(sums, gix, fcW, fcb, out);
}